// Round 1
// 1030.664 us; speedup vs baseline: 1.2050x; 1.2050x over previous
//
#include <hip/hip_runtime.h>

// FNO layer: rfftn -> fftshift -> crop(32x32x32 modes) -> einsum(boixy,iotxy->botxy)
// -> scatter -> fftshift -> irfftn.  Separable dense DFT stages with radix-2
// butterflies exploited at every stage (input-pair split on forward, output-pair
// split on inverse), + memory-bound einsum.  All fp32.
//
// Mode maps (derived from numpy fftshift/roll semantics):
//   forward Y (rfft len 65):  block j -> bin fy(j) = (j-16) mod 65  (j<16: j+49, j>=16: j-16)
//   forward X (fft len 128):  block l -> freq (l-16)       phase e^{-2pi i (l-16) x/128}
//   forward T:                i in [0,32), phase e^{-2pi i i tau/64}
//   inverse T:                e^{+2pi i t tau/64} / (64*128*128)   (all norm folded here)
//   inverse X:                e^{+2pi i (l-16) Xp/128}
//   inverse Y (irfft):        block j lands at bin g(j) = (j+48) mod 65 (double fftshift on odd axis!)
//                             out += s_j*(Re*cos - Im*sin), s_j=2 except bins 0/64 (j=17/16): s=1, Im ignored.
//
// Radix-2 identities used:
//   fwd X:  tw[x+64][l] = (-1)^l tw[x][l]          -> u_e/u_o input split, loop x<64
//   fwd Y:  tw[y+64][j] = (-1)^{f(j)} tw[y][j]     -> per-lane sign, loop y<64
//   fwd T:  tw[tau+32][i] = (-1)^i tw[tau][i]      -> input split, loop tau<32
//   inv T:  tw[t][tau+32] = (-1)^t tw[t][tau]      -> OUTPUT butterfly (tau, tau+32)
//   inv X:  tw[Xp+64][l] = (-1)^l tw[Xp][l]        -> OUTPUT butterfly (Xp, Xp+64)
//   inv Y:  tw[j][Yp+64] = (-1)^{g(j)} tw[j][Yp]   -> OUTPUT butterfly (Yp, Yp+64)

#define PI_F 3.14159265358979323846f

// ---- ws layout (bytes) ----
static constexpr size_t OFF_TWFX  = 0;                    // [x=128][l=32] float2  32KB (only x<64 used)
static constexpr size_t OFF_TWFY  = 32768;                // [y=128][j=32] float2  32KB (only y<64 used)
static constexpr size_t OFF_TWFT  = 65536;                // [tau=64][i=32] float2 16KB (only tau<32 used)
static constexpr size_t OFF_TWIT  = 81920;                // [tau=64][t=32] float2 16KB (only tau<32 used; incl 1/1048576)
static constexpr size_t OFF_TWIX  = 98304;                // [Xp=128][l=32] float2 32KB (only Xp<64 used)
static constexpr size_t OFF_TWIYR = 131072;               // [j=32][Yp=128] float  16KB (only Yp<64 used)
static constexpr size_t OFF_TWIYI = 147456;               // 16KB
static constexpr size_t OFF_A     = 163840;               // S1 (fwd-x out) / S6 (inv-x out): 134217728 B
static constexpr size_t OFF_C     = OFF_A;                // S3 (block)   : 16777216 B (A is dead then)
static constexpr size_t OFF_D     = OFF_A + 16777216ULL;  // S4 (einsum out): 16777216 B
static constexpr size_t OFF_B     = OFF_A + 134217728ULL; // S2 (fwd-y out) / S5 (inv-t out): 33554432 B
// total ws need: OFF_B + 33554432 = 167,936,000 bytes (~160.2 MiB)

__device__ __forceinline__ void cmadd(float2& a, float2 u, float2 v) {
  a.x = fmaf(u.x, v.x, fmaf(-u.y, v.y, a.x));
  a.y = fmaf(u.x, v.y, fmaf( u.y, v.x, a.y));
}

// ---------------- twiddle tables ----------------
__global__ void init_tables(char* __restrict__ ws) {
  int idx = blockIdx.x * 256 + threadIdx.x;
  if (idx >= 20480) return;
  float2* twFX  = (float2*)(ws + OFF_TWFX);
  float2* twFY  = (float2*)(ws + OFF_TWFY);
  float2* twFT  = (float2*)(ws + OFF_TWFT);
  float2* twIT  = (float2*)(ws + OFF_TWIT);
  float2* twIX  = (float2*)(ws + OFF_TWIX);
  float*  twIYr = (float*)(ws + OFF_TWIYR);
  float*  twIYi = (float*)(ws + OFF_TWIYI);

  if (idx < 4096) {                       // twFX [x][l]
    int x = idx >> 5, l = idx & 31;
    int r = (((l - 16) * x) % 128 + 128) % 128;
    float a = -2.0f * PI_F * (float)r / 128.0f;
    float s, c; sincosf(a, &s, &c);
    twFX[idx] = make_float2(c, s);
  } else if (idx < 8192) {                // twFY [y][j]
    int k = idx - 4096;
    int y = k >> 5, j = k & 31;
    int f = (j >= 16) ? (j - 16) : (j + 49);
    int r = (f * y) % 128;
    float a = -2.0f * PI_F * (float)r / 128.0f;
    float s, c; sincosf(a, &s, &c);
    twFY[k] = make_float2(c, s);
  } else if (idx < 10240) {               // twFT [tau][i]
    int k = idx - 8192;
    int tau = k >> 5, i = k & 31;
    int r = (i * tau) % 64;
    float a = -2.0f * PI_F * (float)r / 64.0f;
    float s, c; sincosf(a, &s, &c);
    twFT[k] = make_float2(c, s);
  } else if (idx < 12288) {               // twIT [tau][t], includes 1/(64*128*128)
    int k = idx - 10240;
    int tau = k >> 5, t = k & 31;
    int r = (t * tau) % 64;
    float a = 2.0f * PI_F * (float)r / 64.0f;
    float s, c; sincosf(a, &s, &c);
    const float n = 1.0f / 1048576.0f;
    twIT[k] = make_float2(c * n, s * n);
  } else if (idx < 16384) {               // twIX [Xp][l]
    int k = idx - 12288;
    int Xp = k >> 5, l = k & 31;
    int r = (((l - 16) * Xp) % 128 + 128) % 128;
    float a = 2.0f * PI_F * (float)r / 128.0f;
    float s, c; sincosf(a, &s, &c);
    twIX[k] = make_float2(c, s);
  } else {                                // twIY [j][Yp]
    int k = idx - 16384;
    int j = k >> 7, Yp = k & 127;
    int g = (j + 48) % 65;                // final rfft bin
    int r = (g * Yp) % 128;
    float a = 2.0f * PI_F * (float)r / 128.0f;
    float s, c; sincosf(a, &s, &c);
    bool edge = (j == 16) || (j == 17);   // Nyquist / DC: no doubling, Im ignored
    float sc = edge ? 1.0f : 2.0f;
    twIYr[k] = sc * c;
    twIYi[k] = edge ? 0.0f : (-sc * s);
  }
}

// ---------------- forward X: real x (slab 128x128) -> S1 [slab][l=32][y=128] ----------------
// radix-2 over x: out[l] = sum_{x<64} (v[x] + (-1)^l v[x+64]) * tw[x][l]
__global__ void __launch_bounds__(256) k_fwd_x(const float* __restrict__ x,
                                               float2* __restrict__ S1,
                                               const float2* __restrict__ twFX) {
  __shared__ float2 tw[2048];                         // [x<64][l]
  for (int i = threadIdx.x; i < 2048; i += 256) tw[i] = twFX[i];
  __syncthreads();
  int slab = blockIdx.x * 2 + (threadIdx.x >> 7);     // (b*32+c)*64+tau
  int y = threadIdx.x & 127;
  const float* xp = x + (size_t)slab * 16384;
  float2 acc[32];
#pragma unroll
  for (int l = 0; l < 32; ++l) acc[l] = make_float2(0.f, 0.f);
  for (int xx = 0; xx < 64; ++xx) {
    float v0 = xp[xx * 128 + y];
    float v1 = xp[(xx + 64) * 128 + y];
    float ue = v0 + v1;
    float uo = v0 - v1;
    const float2* twr = &tw[xx * 32];
#pragma unroll
    for (int l = 0; l < 32; ++l) {
      float u = (l & 1) ? uo : ue;
      acc[l].x = fmaf(u, twr[l].x, acc[l].x);
      acc[l].y = fmaf(u, twr[l].y, acc[l].y);
    }
  }
  float2* outp = S1 + (size_t)slab * 4096;
#pragma unroll
  for (int l = 0; l < 32; ++l) outp[l * 128 + y] = acc[l];
}

// ---------------- forward Y: S1 rows (len-128 complex) -> S2 [row][j=32] ----------------
// radix-2 over y: out[j] = sum_{y<64} (v[y] + (-1)^{f(j)} v[y+64]) * tw[y][j]
// f(j) parity: j<16: f=j+49 (odd iff j even);  j>=16: f=j-16 (odd iff j odd)
__global__ void __launch_bounds__(256) k_fwd_y(const float2* __restrict__ S1,
                                               float2* __restrict__ S2,
                                               const float2* __restrict__ twFY) {
  __shared__ float2 tw[2048];    // [y<64][j] 16KB
  __shared__ float2 rows[2048];  // 16 rows x 128  16KB
  for (int i = threadIdx.x; i < 2048; i += 256) tw[i] = twFY[i];
  const float2* src = S1 + (size_t)blockIdx.x * 2048;
  for (int i = threadIdx.x; i < 2048; i += 256) rows[i] = src[i];
  __syncthreads();
  int j = threadIdx.x & 31;
  int rslot = threadIdx.x >> 5;  // 0..7
  bool fodd = (j < 16) ? ((j & 1) == 0) : ((j & 1) == 1);
  float sgn = fodd ? -1.0f : 1.0f;
  float2 acc[2];
  acc[0] = make_float2(0.f, 0.f);
  acc[1] = make_float2(0.f, 0.f);
  for (int y = 0; y < 64; ++y) {
    float2 t = tw[y * 32 + j];
#pragma unroll
    for (int k = 0; k < 2; ++k) {
      float2 a = rows[(rslot * 2 + k) * 128 + y];
      float2 b = rows[(rslot * 2 + k) * 128 + y + 64];
      float2 u = make_float2(fmaf(sgn, b.x, a.x), fmaf(sgn, b.y, a.y));
      cmadd(acc[k], u, t);
    }
  }
  float2* dst = S2 + (size_t)blockIdx.x * 16 * 32;
#pragma unroll
  for (int k = 0; k < 2; ++k) dst[(rslot * 2 + k) * 32 + j] = acc[k];
}

// ---------------- forward T: S2 [bc][tau=64][site=1024] -> S3 [bc][i=32][site] ----------------
// radix-2 over tau: out[i] = sum_{tau<32} (v[tau] + (-1)^i v[tau+32]) * tw[tau][i]
__global__ void __launch_bounds__(256) k_fwd_t(const float2* __restrict__ S2,
                                               float2* __restrict__ S3,
                                               const float2* __restrict__ twFT) {
  __shared__ float2 tw[1024];    // [tau<32][i]
  for (int i = threadIdx.x; i < 1024; i += 256) tw[i] = twFT[i];
  __syncthreads();
  int bc = blockIdx.x >> 3;
  int sg = (blockIdx.x >> 1) & 3;
  int ih = blockIdx.x & 1;
  int s = sg * 256 + threadIdx.x;
  const float2* in = S2 + (size_t)bc * 65536 + s;
  float2 acc[16];
#pragma unroll
  for (int q = 0; q < 16; ++q) acc[q] = make_float2(0.f, 0.f);
  for (int tau = 0; tau < 32; ++tau) {
    float2 v0 = in[(size_t)tau * 1024];
    float2 v1 = in[(size_t)(tau + 32) * 1024];
    float2 ue = make_float2(v0.x + v1.x, v0.y + v1.y);
    float2 uo = make_float2(v0.x - v1.x, v0.y - v1.y);
    const float2* twr = &tw[tau * 32 + ih * 16];
#pragma unroll
    for (int q = 0; q < 16; ++q) cmadd(acc[q], (q & 1) ? uo : ue, twr[q]);
  }
  float2* outp = S3 + (size_t)bc * 32768 + (size_t)(ih * 16) * 1024 + s;
#pragma unroll
  for (int q = 0; q < 16; ++q) outp[(size_t)q * 1024] = acc[q];
}

// ---------------- einsum: out[b,o,t,s] = sum_i block[b,o,i,s] * (wr+i wi)[i,o,t,s] ----------------
__global__ void __launch_bounds__(256, 2) k_einsum(const float2* __restrict__ S3,
                                                   const float* __restrict__ wr,
                                                   const float* __restrict__ wi,
                                                   float2* __restrict__ S4) {
  int o  = blockIdx.x >> 4;
  int tc = (blockIdx.x >> 2) & 3;
  int sg = blockIdx.x & 3;
  int s = sg * 256 + threadIdx.x;
  float2 blk0[32], blk1[32];
#pragma unroll
  for (int i = 0; i < 32; ++i) {
    blk0[i] = S3[(size_t)(o * 32 + i) * 1024 + s];
    blk1[i] = S3[(size_t)((32 + o) * 32 + i) * 1024 + s];
  }
  for (int tt = 0; tt < 8; ++tt) {
    int t = tc * 8 + tt;
    float2 a0 = make_float2(0.f, 0.f), a1 = make_float2(0.f, 0.f);
#pragma unroll
    for (int i = 0; i < 32; ++i) {
      size_t widx = (size_t)((i * 32 + o) * 32 + t) * 1024 + s;
      float r = wr[widx], m = wi[widx];
      a0.x = fmaf(blk0[i].x, r, fmaf(-blk0[i].y, m, a0.x));
      a0.y = fmaf(blk0[i].x, m, fmaf( blk0[i].y, r, a0.y));
      a1.x = fmaf(blk1[i].x, r, fmaf(-blk1[i].y, m, a1.x));
      a1.y = fmaf(blk1[i].x, m, fmaf( blk1[i].y, r, a1.y));
    }
    S4[(size_t)(o * 32 + t) * 1024 + s] = a0;
    S4[(size_t)((32 + o) * 32 + t) * 1024 + s] = a1;
  }
}

// ---------------- inverse T: S4 [bo][t=32][site] -> S5 [bo][tau=64][site] ----------------
// OUTPUT butterfly: out[tau]   = e + o,  out[tau+32] = e - o
//   e = sum_{even t} in[t] tw[tau][t],  o = sum_{odd t} ...   (tau < 32)
__global__ void __launch_bounds__(256) k_inv_t(const float2* __restrict__ S4,
                                               float2* __restrict__ S5,
                                               const float2* __restrict__ twIT) {
  __shared__ float2 tw[1024];    // [tau<32][t]
  for (int i = threadIdx.x; i < 1024; i += 256) tw[i] = twIT[i];
  __syncthreads();
  int bo = blockIdx.x >> 2;      // 256 blocks: bo(64) x sg(4)
  int sg = blockIdx.x & 3;
  int s = sg * 256 + threadIdx.x;
  float2 in[32];
#pragma unroll
  for (int t = 0; t < 32; ++t) in[t] = S4[(size_t)bo * 32768 + (size_t)t * 1024 + s];
  float2* outp = S5 + (size_t)bo * 65536 + s;
  for (int tau = 0; tau < 32; ++tau) {
    float2 e = make_float2(0.f, 0.f), o = make_float2(0.f, 0.f);
    const float2* twr = &tw[tau * 32];
#pragma unroll
    for (int t = 0; t < 32; ++t) cmadd((t & 1) ? o : e, in[t], twr[t]);
    outp[(size_t)tau * 1024]        = make_float2(e.x + o.x, e.y + o.y);
    outp[(size_t)(tau + 32) * 1024] = make_float2(e.x - o.x, e.y - o.y);
  }
}

// ---------------- inverse X: S5 slab [l=32][j=32] -> S6 [slab][Xp=128][j=32] ----------------
// OUTPUT butterfly: out[Xp] = e + o, out[Xp+64] = e - o  (e: even l, o: odd l; Xp < 64)
// input modes held in registers (read once from LDS), twiddles broadcast from LDS.
__global__ void __launch_bounds__(256) k_inv_x(const float2* __restrict__ S5,
                                               float2* __restrict__ S6,
                                               const float2* __restrict__ twIX) {
  __shared__ float2 tw[2048];    // [Xp<64][l] 16KB
  __shared__ float4 inb4[512];   // [l][j] 8KB (float4 for 16B staging loads)
  float2* inb_s = (float2*)inb4;
  for (int i = threadIdx.x; i < 2048; i += 256) tw[i] = twIX[i];
  const float4* src4 = (const float4*)(S5 + (size_t)blockIdx.x * 1024);
  for (int i = threadIdx.x; i < 512; i += 256) inb4[i] = src4[i];
  __syncthreads();
  int j  = threadIdx.x & 31;
  int xs = threadIdx.x >> 5;     // 0..7, each handles 8 Xp-pairs
  float2 inb[32];
#pragma unroll
  for (int l = 0; l < 32; ++l) inb[l] = inb_s[l * 32 + j];
  float2* dst = S6 + (size_t)blockIdx.x * 4096;
  for (int it = 0; it < 8; ++it) {
    int Xp = xs * 8 + it;        // 0..63
    float2 e = make_float2(0.f, 0.f), o = make_float2(0.f, 0.f);
    const float2* twr = &tw[Xp * 32];
#pragma unroll
    for (int l = 0; l < 32; ++l) cmadd((l & 1) ? o : e, inb[l], twr[l]);
    dst[Xp * 32 + j]        = make_float2(e.x + o.x, e.y + o.y);
    dst[(Xp + 64) * 32 + j] = make_float2(e.x - o.x, e.y - o.y);
  }
}

// ---------------- inverse Y (irfft): S6 rows [32 modes] -> out rows [128 real] ----------------
// OUTPUT butterfly over Yp: tw[j][Yp+64] = (-1)^{g(j)} tw[j][Yp].
//   g(j) even iff (j<=16 && j even) || (j>=17 && j odd).
//   out[Yp] = E + O, out[Yp+64] = E - O, E = sum_{g even} c_j, O = sum_{g odd} c_j,
//   c_j = v.x*cr[j] + v.y*ci[j].
// 256 threads: Yp = tid&63 (0..63), rg = tid>>6 selects 16 of the block's 64 rows.
// 4 independent accumulator chains (e0,e1,o0,o1) to cover FMA latency.
__global__ void __launch_bounds__(256) k_inv_y(const float2* __restrict__ S6,
                                               float* __restrict__ out,
                                               const float* __restrict__ twIYr,
                                               const float* __restrict__ twIYi) {
  __shared__ float4 rows4[1024];  // 64 rows x 32 modes, 16KB
  float2* rows = (float2*)rows4;
  const float4* src4 = (const float4*)(S6 + (size_t)blockIdx.x * 2048);
  for (int i = threadIdx.x; i < 1024; i += 256) rows4[i] = src4[i];
  int Yp = threadIdx.x & 63;
  int rg = threadIdx.x >> 6;     // 0..3
  float cr[32], ci[32];
#pragma unroll
  for (int jj = 0; jj < 32; ++jj) {
    cr[jj] = twIYr[jj * 128 + Yp];
    ci[jj] = twIYi[jj * 128 + Yp];
  }
  __syncthreads();
  float* dst = out + (size_t)blockIdx.x * 8192;
  for (int rr = 0; rr < 16; ++rr) {
    int r = rg * 16 + rr;
    float e0 = 0.f, e1 = 0.f, o0 = 0.f, o1 = 0.f;
#pragma unroll
    for (int jj = 0; jj < 32; ++jj) {
      float2 v = rows[r * 32 + jj];
      const bool ge = (jj <= 16) ? ((jj & 1) == 0) : ((jj & 1) == 1);
      const int half = (jj >> 1) & 1;
      float& tgt = ge ? (half ? e1 : e0) : (half ? o1 : o0);
      tgt = fmaf(v.x, cr[jj], fmaf(v.y, ci[jj], tgt));
    }
    float E = e0 + e1, O = o0 + o1;
    dst[(size_t)r * 128 + Yp]      = E + O;
    dst[(size_t)r * 128 + Yp + 64] = E - O;
  }
}

extern "C" void kernel_launch(void* const* d_in, const int* in_sizes, int n_in,
                              void* d_out, int out_size, void* d_ws, size_t ws_size,
                              hipStream_t stream) {
  (void)in_sizes; (void)n_in; (void)out_size; (void)ws_size;
  const float* x  = (const float*)d_in[0];
  const float* wr = (const float*)d_in[1];
  const float* wi = (const float*)d_in[2];
  float* out = (float*)d_out;
  char* ws = (char*)d_ws;

  const float2* twFX  = (const float2*)(ws + OFF_TWFX);
  const float2* twFY  = (const float2*)(ws + OFF_TWFY);
  const float2* twFT  = (const float2*)(ws + OFF_TWFT);
  const float2* twIT  = (const float2*)(ws + OFF_TWIT);
  const float2* twIX  = (const float2*)(ws + OFF_TWIX);
  const float*  twIYr = (const float*)(ws + OFF_TWIYR);
  const float*  twIYi = (const float*)(ws + OFF_TWIYI);
  float2* S1 = (float2*)(ws + OFF_A);
  float2* S2 = (float2*)(ws + OFF_B);
  float2* S3 = (float2*)(ws + OFF_C);
  float2* S4 = (float2*)(ws + OFF_D);
  float2* S5 = (float2*)(ws + OFF_B);   // aliases S2 (dead)
  float2* S6 = (float2*)(ws + OFF_A);   // aliases S1 (dead)

  init_tables<<<dim3(80), dim3(256), 0, stream>>>(ws);
  k_fwd_x <<<dim3(2048), dim3(256), 0, stream>>>(x, S1, twFX);
  k_fwd_y <<<dim3(8192), dim3(256), 0, stream>>>(S1, S2, twFY);
  k_fwd_t <<<dim3(512),  dim3(256), 0, stream>>>(S2, S3, twFT);
  k_einsum<<<dim3(512),  dim3(256), 0, stream>>>(S3, wr, wi, S4);
  k_inv_t <<<dim3(256),  dim3(256), 0, stream>>>(S4, S5, twIT);
  k_inv_x <<<dim3(4096), dim3(256), 0, stream>>>(S5, S6, twIX);
  k_inv_y <<<dim3(8192), dim3(256), 0, stream>>>(S6, out, twIYr, twIYi);
}

// Round 2
// 903.822 us; speedup vs baseline: 1.3742x; 1.1403x over previous
//
#include <hip/hip_runtime.h>

// FNO layer: rfftn -> fftshift -> crop(32x32x32 modes) -> einsum(boixy,iotxy->botxy)
// -> scatter -> fftshift -> irfftn.  Separable dense DFT stages with radix-2
// butterflies at every stage; spatial X/Y stages FUSED per slab through LDS
// (no 134MB intermediate round-trips).  All fp32.
//
// Mode maps (derived from numpy fftshift/roll semantics):
//   forward Y (rfft len 65):  block j -> bin fy(j) = (j-16) mod 65  (j<16: j+49, j>=16: j-16)
//   forward X (fft len 128):  block l -> freq (l-16)       phase e^{-2pi i (l-16) x/128}
//   forward T:                i in [0,32), phase e^{-2pi i i tau/64}
//   inverse T:                e^{+2pi i t tau/64} / (64*128*128)   (all norm folded here)
//   inverse X:                e^{+2pi i (l-16) Xp/128}
//   inverse Y (irfft):        block j lands at bin g(j) = (j+48) mod 65 (double fftshift on odd axis!)
//                             out += s_j*(Re*cos - Im*sin), s_j=2 except bins 0/64 (j=17/16): s=1, Im ignored.
//
// Radix-2 identities used:
//   fwd X:  tw[x+64][l] = (-1)^l tw[x][l]          -> u_e/u_o input split, loop x<64
//   fwd Y:  tw[y+64][j] = (-1)^{f(j)} tw[y][j]     -> per-lane sign, loop y<64
//   fwd T:  tw[tau+32][i] = (-1)^i tw[tau][i]      -> input split, loop tau<32
//   inv T:  tw[t][tau+32] = (-1)^t tw[t][tau]      -> OUTPUT butterfly (tau, tau+32)
//   inv X:  tw[Xp+64][l] = (-1)^l tw[Xp][l]        -> OUTPUT butterfly (Xp, Xp+64)
//   inv Y:  tw[j][Yp+64] = (-1)^{g(j)} tw[j][Yp]   -> OUTPUT butterfly (Yp, Yp+64)

#define PI_F 3.14159265358979323846f

// ---- ws layout (bytes) ----
static constexpr size_t OFF_TWFX  = 0;                    // [x=128][l=32] float2  32KB (only x<64 used)
static constexpr size_t OFF_TWFY  = 32768;                // [y=128][j=32] float2  32KB (only y<64 used)
static constexpr size_t OFF_TWFT  = 65536;                // [tau=64][i=32] float2 16KB (only tau<32 used)
static constexpr size_t OFF_TWIT  = 81920;                // [tau=64][t=32] float2 16KB (only tau<32 used; incl 1/1048576)
static constexpr size_t OFF_TWIX  = 98304;                // [Xp=128][l=32] float2 32KB (only Xp<64 used)
static constexpr size_t OFF_TWIYR = 131072;               // [j=32][Yp=128] float  16KB (only Yp<64 used)
static constexpr size_t OFF_TWIYI = 147456;               // 16KB
static constexpr size_t OFF_A     = 163840;               // S3 (block): 16777216 B
static constexpr size_t OFF_C     = OFF_A;                // S3
static constexpr size_t OFF_D     = OFF_A + 16777216ULL;  // S4 (einsum out): 16777216 B
static constexpr size_t OFF_B     = OFF_A + 134217728ULL; // S2 (fwd out) / S5 (inv-t out): 33554432 B

__device__ __forceinline__ void cmadd(float2& a, float2 u, float2 v) {
  a.x = fmaf(u.x, v.x, fmaf(-u.y, v.y, a.x));
  a.y = fmaf(u.x, v.y, fmaf( u.y, v.x, a.y));
}

// ---------------- twiddle tables ----------------
__global__ void init_tables(char* __restrict__ ws) {
  int idx = blockIdx.x * 256 + threadIdx.x;
  if (idx >= 20480) return;
  float2* twFX  = (float2*)(ws + OFF_TWFX);
  float2* twFY  = (float2*)(ws + OFF_TWFY);
  float2* twFT  = (float2*)(ws + OFF_TWFT);
  float2* twIT  = (float2*)(ws + OFF_TWIT);
  float2* twIX  = (float2*)(ws + OFF_TWIX);
  float*  twIYr = (float*)(ws + OFF_TWIYR);
  float*  twIYi = (float*)(ws + OFF_TWIYI);

  if (idx < 4096) {                       // twFX [x][l]
    int x = idx >> 5, l = idx & 31;
    int r = (((l - 16) * x) % 128 + 128) % 128;
    float a = -2.0f * PI_F * (float)r / 128.0f;
    float s, c; sincosf(a, &s, &c);
    twFX[idx] = make_float2(c, s);
  } else if (idx < 8192) {                // twFY [y][j]
    int k = idx - 4096;
    int y = k >> 5, j = k & 31;
    int f = (j >= 16) ? (j - 16) : (j + 49);
    int r = (f * y) % 128;
    float a = -2.0f * PI_F * (float)r / 128.0f;
    float s, c; sincosf(a, &s, &c);
    twFY[k] = make_float2(c, s);
  } else if (idx < 10240) {               // twFT [tau][i]
    int k = idx - 8192;
    int tau = k >> 5, i = k & 31;
    int r = (i * tau) % 64;
    float a = -2.0f * PI_F * (float)r / 64.0f;
    float s, c; sincosf(a, &s, &c);
    twFT[k] = make_float2(c, s);
  } else if (idx < 12288) {               // twIT [tau][t], includes 1/(64*128*128)
    int k = idx - 10240;
    int tau = k >> 5, t = k & 31;
    int r = (t * tau) % 64;
    float a = 2.0f * PI_F * (float)r / 64.0f;
    float s, c; sincosf(a, &s, &c);
    const float n = 1.0f / 1048576.0f;
    twIT[k] = make_float2(c * n, s * n);
  } else if (idx < 16384) {               // twIX [Xp][l]
    int k = idx - 12288;
    int Xp = k >> 5, l = k & 31;
    int r = (((l - 16) * Xp) % 128 + 128) % 128;
    float a = 2.0f * PI_F * (float)r / 128.0f;
    float s, c; sincosf(a, &s, &c);
    twIX[k] = make_float2(c, s);
  } else {                                // twIY [j][Yp]
    int k = idx - 16384;
    int j = k >> 7, Yp = k & 127;
    int g = (j + 48) % 65;                // final rfft bin
    int r = (g * Yp) % 128;
    float a = 2.0f * PI_F * (float)r / 128.0f;
    float s, c; sincosf(a, &s, &c);
    bool edge = (j == 16) || (j == 17);   // Nyquist / DC: no doubling, Im ignored
    float sc = edge ? 1.0f : 2.0f;
    twIYr[k] = sc * c;
    twIYi[k] = edge ? 0.0f : (-sc * s);
  }
}

// ---------------- fused forward X+Y: x slab (128x128 real) -> S2 [slab][l=32][j=32] ----------------
// Phase 1 (X-DFT, radix-2 over x): mid[l][y] = sum_{x<64} (v0 +/- v1) * twFX[x][l]
// Phase 2 (Y-DFT, radix-2 over y): S2[l][j] = sum_{y<64} (mid[l][y] + sgn(j)*mid[l][y+64]) * twFY[y][j]
__global__ void __launch_bounds__(256) k_fwd_xy(const float* __restrict__ x,
                                                float2* __restrict__ S2,
                                                const float2* __restrict__ twFXg,
                                                const float2* __restrict__ twFYg) {
  __shared__ float4 twX4[1024];          // [x<64][l] float2, 16KB
  __shared__ float4 twY4[1024];          // [y<64][j] float2, 16KB
  __shared__ float2 mid[4096];           // [l=32][y=128], 32KB
  float2* twX = (float2*)twX4;
  float2* twY = (float2*)twY4;
  for (int i = threadIdx.x; i < 2048; i += 256) { twX[i] = twFXg[i]; twY[i] = twFYg[i]; }
  __syncthreads();

  int slab = blockIdx.x;                 // (b*32+c)*64 + tau
  const float* xp = x + (size_t)slab * 16384;

  // ---- phase 1: X-DFT ----
  {
    int y  = threadIdx.x & 127;
    int lh = threadIdx.x >> 7;           // 0..1 -> l range lh*16 .. +16
    float2 acc[16];
#pragma unroll
    for (int q = 0; q < 16; ++q) acc[q] = make_float2(0.f, 0.f);
    for (int xx = 0; xx < 64; ++xx) {
      float v0 = xp[xx * 128 + y];
      float v1 = xp[(xx + 64) * 128 + y];
      float ue = v0 + v1;
      float uo = v0 - v1;
      const float4* twr4 = (const float4*)&twX[xx * 32 + lh * 16];
#pragma unroll
      for (int p = 0; p < 8; ++p) {      // l = lh*16 + 2p (even -> ue), +1 (odd -> uo)
        float4 q4 = twr4[p];
        acc[2 * p].x     = fmaf(ue, q4.x, acc[2 * p].x);
        acc[2 * p].y     = fmaf(ue, q4.y, acc[2 * p].y);
        acc[2 * p + 1].x = fmaf(uo, q4.z, acc[2 * p + 1].x);
        acc[2 * p + 1].y = fmaf(uo, q4.w, acc[2 * p + 1].y);
      }
    }
#pragma unroll
    for (int q = 0; q < 16; ++q) mid[(lh * 16 + q) * 128 + y] = acc[q];
  }
  __syncthreads();

  // ---- phase 2: Y-DFT ----
  {
    int j  = threadIdx.x & 31;
    int lg = threadIdx.x >> 5;           // 0..7 -> rows l = lg*4 .. +4
    bool fodd = (j < 16) ? ((j & 1) == 0) : ((j & 1) == 1);
    float sgn = fodd ? -1.0f : 1.0f;
    float2 acc2[4];
#pragma unroll
    for (int k = 0; k < 4; ++k) acc2[k] = make_float2(0.f, 0.f);
    for (int y = 0; y < 64; ++y) {
      float2 t = twY[y * 32 + j];
#pragma unroll
      for (int k = 0; k < 4; ++k) {
        float2 a = mid[(lg * 4 + k) * 128 + y];
        float2 b = mid[(lg * 4 + k) * 128 + y + 64];
        float2 u = make_float2(fmaf(sgn, b.x, a.x), fmaf(sgn, b.y, a.y));
        cmadd(acc2[k], u, t);
      }
    }
    float2* dst = S2 + (size_t)slab * 1024;
#pragma unroll
    for (int k = 0; k < 4; ++k) dst[(lg * 4 + k) * 32 + j] = acc2[k];
  }
}

// ---------------- forward T: S2 [bc][tau=64][site=1024] -> S3 [bc][i=32][site] ----------------
// radix-2 over tau: out[i] = sum_{tau<32} (v[tau] + (-1)^i v[tau+32]) * tw[tau][i]
// grid 1024 = bc(64) x sg(8) x ih(2); thread covers 8 i's (iq = tid>>7).
__global__ void __launch_bounds__(256) k_fwd_t(const float2* __restrict__ S2,
                                               float2* __restrict__ S3,
                                               const float2* __restrict__ twFT) {
  __shared__ float4 tw4[512];    // [tau<32][i] float2
  float2* tw = (float2*)tw4;
  for (int i = threadIdx.x; i < 1024; i += 256) tw[i] = twFT[i];
  __syncthreads();
  int bc = blockIdx.x >> 4;
  int sg = (blockIdx.x >> 1) & 7;
  int ih = blockIdx.x & 1;
  int s  = sg * 128 + (threadIdx.x & 127);
  int ibase = ih * 16 + (threadIdx.x >> 7) * 8;   // 8 i's per thread, ibase even
  const float2* in = S2 + (size_t)bc * 65536 + s;
  float2 acc[8];
#pragma unroll
  for (int q = 0; q < 8; ++q) acc[q] = make_float2(0.f, 0.f);
  for (int tau = 0; tau < 32; ++tau) {
    float2 v0 = in[(size_t)tau * 1024];
    float2 v1 = in[(size_t)(tau + 32) * 1024];
    float2 ue = make_float2(v0.x + v1.x, v0.y + v1.y);
    float2 uo = make_float2(v0.x - v1.x, v0.y - v1.y);
    const float4* twr4 = (const float4*)&tw[tau * 32 + ibase];
#pragma unroll
    for (int p = 0; p < 4; ++p) {        // i = ibase+2p even -> ue; odd -> uo
      float4 q4 = twr4[p];
      cmadd(acc[2 * p],     ue, make_float2(q4.x, q4.y));
      cmadd(acc[2 * p + 1], uo, make_float2(q4.z, q4.w));
    }
  }
  float2* outp = S3 + (size_t)bc * 32768 + (size_t)ibase * 1024 + s;
#pragma unroll
  for (int q = 0; q < 8; ++q) outp[(size_t)q * 1024] = acc[q];
}

// ---------------- einsum: out[b,o,t,s] = sum_i block[b,o,i,s] * (wr+i wi)[i,o,t,s] ----------------
// grid 1024 = o(32) x tc(8) x sg(4); 4 t per block; i-reduction chunked 2x16 to halve blk regs.
__global__ void __launch_bounds__(256, 4) k_einsum(const float2* __restrict__ S3,
                                                   const float* __restrict__ wr,
                                                   const float* __restrict__ wi,
                                                   float2* __restrict__ S4) {
  int o  = blockIdx.x >> 5;
  int tc = (blockIdx.x >> 2) & 7;
  int sg = blockIdx.x & 3;
  int s = sg * 256 + threadIdx.x;
  float2 acc0[4], acc1[4];
#pragma unroll
  for (int tt = 0; tt < 4; ++tt) { acc0[tt] = make_float2(0.f, 0.f); acc1[tt] = make_float2(0.f, 0.f); }
#pragma unroll 1
  for (int ic = 0; ic < 2; ++ic) {
    float2 blk0[16], blk1[16];
#pragma unroll
    for (int q = 0; q < 16; ++q) {
      int i = ic * 16 + q;
      blk0[q] = S3[(size_t)(o * 32 + i) * 1024 + s];
      blk1[q] = S3[(size_t)((32 + o) * 32 + i) * 1024 + s];
    }
#pragma unroll
    for (int q = 0; q < 16; ++q) {
      int i = ic * 16 + q;
      size_t base = (size_t)((i * 32 + o) * 32 + tc * 4) * 1024 + s;
      float2 b0 = blk0[q], b1 = blk1[q];
#pragma unroll
      for (int tt = 0; tt < 4; ++tt) {
        float r = wr[base + (size_t)tt * 1024];
        float m = wi[base + (size_t)tt * 1024];
        acc0[tt].x = fmaf(b0.x, r, fmaf(-b0.y, m, acc0[tt].x));
        acc0[tt].y = fmaf(b0.x, m, fmaf( b0.y, r, acc0[tt].y));
        acc1[tt].x = fmaf(b1.x, r, fmaf(-b1.y, m, acc1[tt].x));
        acc1[tt].y = fmaf(b1.x, m, fmaf( b1.y, r, acc1[tt].y));
      }
    }
  }
#pragma unroll
  for (int tt = 0; tt < 4; ++tt) {
    int t = tc * 4 + tt;
    S4[(size_t)(o * 32 + t) * 1024 + s] = acc0[tt];
    S4[(size_t)((32 + o) * 32 + t) * 1024 + s] = acc1[tt];
  }
}

// ---------------- inverse T: S4 [bo][t=32][site] -> S5 [bo][tau=64][site] ----------------
// OUTPUT butterfly: out[tau] = e + o, out[tau+32] = e - o  (tau < 32)
// grid 1024 = bo(64) x sg(16); thread covers 8 tau-pairs (tq = tid>>6).
__global__ void __launch_bounds__(256) k_inv_t(const float2* __restrict__ S4,
                                               float2* __restrict__ S5,
                                               const float2* __restrict__ twIT) {
  __shared__ float4 tw4[512];    // [tau<32][t] float2
  float2* tw = (float2*)tw4;
  for (int i = threadIdx.x; i < 1024; i += 256) tw[i] = twIT[i];
  __syncthreads();
  int bo = blockIdx.x >> 4;
  int sg = blockIdx.x & 15;
  int s  = sg * 64 + (threadIdx.x & 63);
  int tq = threadIdx.x >> 6;     // 0..3
  float2 in[32];
#pragma unroll
  for (int t = 0; t < 32; ++t) in[t] = S4[(size_t)bo * 32768 + (size_t)t * 1024 + s];
  float2* outp = S5 + (size_t)bo * 65536 + s;
  for (int tt = 0; tt < 8; ++tt) {
    int tau = tq * 8 + tt;
    float2 e = make_float2(0.f, 0.f), o = make_float2(0.f, 0.f);
    const float4* twr4 = (const float4*)&tw[tau * 32];
#pragma unroll
    for (int p = 0; p < 16; ++p) {       // t = 2p even -> e; odd -> o
      float4 q4 = twr4[p];
      cmadd(e, in[2 * p],     make_float2(q4.x, q4.y));
      cmadd(o, in[2 * p + 1], make_float2(q4.z, q4.w));
    }
    outp[(size_t)tau * 1024]        = make_float2(e.x + o.x, e.y + o.y);
    outp[(size_t)(tau + 32) * 1024] = make_float2(e.x - o.x, e.y - o.y);
  }
}

// ---------------- fused inverse X+Y: S5 slab [l=32][j=32] -> out slab [Xp=128][Yp=128] real ----------------
// Phase 1 (inv-X, output butterfly over Xp): mid[Xp][j] = e+o, mid[Xp+64][j] = e-o
// Phase 2 (inv-Y irfft, output butterfly over Yp): out[Xp][Yp] = E+O, out[Xp][Yp+64] = E-O
__global__ void __launch_bounds__(256) k_inv_xy(const float2* __restrict__ S5,
                                                float* __restrict__ out,
                                                const float2* __restrict__ twIXg,
                                                const float* __restrict__ twIYr,
                                                const float* __restrict__ twIYi) {
  __shared__ float4 twX4[1024];          // [Xp<64][l] float2, 16KB
  __shared__ float4 inb4[512];           // [l=32][j=32] float2, 8KB
  __shared__ float4 mid4[2048];          // [Xp=128][j=32] float2, 32KB
  float2* twX  = (float2*)twX4;
  float2* inb_s = (float2*)inb4;
  float2* mid  = (float2*)mid4;
  for (int i = threadIdx.x; i < 2048; i += 256) twX[i] = twIXg[i];
  int slab = blockIdx.x;                 // bo*64 + tau
  const float4* src4 = (const float4*)(S5 + (size_t)slab * 1024);
  for (int i = threadIdx.x; i < 512; i += 256) inb4[i] = src4[i];

  // preload inverse-Y twiddles (register, per-lane Yp) while staging completes
  int Yp = threadIdx.x & 63;
  float cr[32], ci[32];
#pragma unroll
  for (int jj = 0; jj < 32; ++jj) {
    cr[jj] = twIYr[jj * 128 + Yp];
    ci[jj] = twIYi[jj * 128 + Yp];
  }
  __syncthreads();

  // ---- phase 1: inverse X ----
  {
    int j  = threadIdx.x & 31;
    int xs = threadIdx.x >> 5;           // 0..7, each 8 Xp-pairs
    float2 inb[32];
#pragma unroll
    for (int l = 0; l < 32; ++l) inb[l] = inb_s[l * 32 + j];
    for (int it = 0; it < 8; ++it) {
      int Xp = xs * 8 + it;              // 0..63
      float2 e = make_float2(0.f, 0.f), o = make_float2(0.f, 0.f);
      const float4* twr4 = (const float4*)&twX[Xp * 32];
#pragma unroll
      for (int p = 0; p < 16; ++p) {     // l = 2p even -> e; odd -> o
        float4 q4 = twr4[p];
        cmadd(e, inb[2 * p],     make_float2(q4.x, q4.y));
        cmadd(o, inb[2 * p + 1], make_float2(q4.z, q4.w));
      }
      mid[Xp * 32 + j]        = make_float2(e.x + o.x, e.y + o.y);
      mid[(Xp + 64) * 32 + j] = make_float2(e.x - o.x, e.y - o.y);
    }
  }
  __syncthreads();

  // ---- phase 2: inverse Y (irfft) ----
  {
    int rg = threadIdx.x >> 6;           // 0..3 (uniform per wave -> broadcast mid reads)
    float* dst = out + (size_t)slab * 16384;
    for (int rr = 0; rr < 32; ++rr) {
      int r = rg * 32 + rr;              // Xp row 0..127
      const float4* row4 = (const float4*)&mid[r * 32];
      float e0 = 0.f, e1 = 0.f, o0 = 0.f, o1 = 0.f;
#pragma unroll
      for (int p = 0; p < 16; ++p) {
        float4 q4 = row4[p];
        {
          int jj = 2 * p;
          const bool ge = (jj <= 16) ? ((jj & 1) == 0) : ((jj & 1) == 1);
          float c = fmaf(q4.x, cr[jj], q4.y * ci[jj]);
          if (ge) { if ((jj >> 1) & 1) e1 += c; else e0 += c; }
          else    { if ((jj >> 1) & 1) o1 += c; else o0 += c; }
        }
        {
          int jj = 2 * p + 1;
          const bool ge = (jj <= 16) ? ((jj & 1) == 0) : ((jj & 1) == 1);
          float c = fmaf(q4.z, cr[jj], q4.w * ci[jj]);
          if (ge) { if ((jj >> 1) & 1) e1 += c; else e0 += c; }
          else    { if ((jj >> 1) & 1) o1 += c; else o0 += c; }
        }
      }
      float E = e0 + e1, O = o0 + o1;
      dst[(size_t)r * 128 + Yp]      = E + O;
      dst[(size_t)r * 128 + Yp + 64] = E - O;
    }
  }
}

extern "C" void kernel_launch(void* const* d_in, const int* in_sizes, int n_in,
                              void* d_out, int out_size, void* d_ws, size_t ws_size,
                              hipStream_t stream) {
  (void)in_sizes; (void)n_in; (void)out_size; (void)ws_size;
  const float* x  = (const float*)d_in[0];
  const float* wr = (const float*)d_in[1];
  const float* wi = (const float*)d_in[2];
  float* out = (float*)d_out;
  char* ws = (char*)d_ws;

  const float2* twFX  = (const float2*)(ws + OFF_TWFX);
  const float2* twFY  = (const float2*)(ws + OFF_TWFY);
  const float2* twFT  = (const float2*)(ws + OFF_TWFT);
  const float2* twIT  = (const float2*)(ws + OFF_TWIT);
  const float2* twIX  = (const float2*)(ws + OFF_TWIX);
  const float*  twIYr = (const float*)(ws + OFF_TWIYR);
  const float*  twIYi = (const float*)(ws + OFF_TWIYI);
  float2* S2 = (float2*)(ws + OFF_B);
  float2* S3 = (float2*)(ws + OFF_C);
  float2* S4 = (float2*)(ws + OFF_D);
  float2* S5 = (float2*)(ws + OFF_B);   // aliases S2 (dead after fwd_t)

  init_tables<<<dim3(80), dim3(256), 0, stream>>>(ws);
  k_fwd_xy<<<dim3(4096), dim3(256), 0, stream>>>(x, S2, twFX, twFY);
  k_fwd_t <<<dim3(1024), dim3(256), 0, stream>>>(S2, S3, twFT);
  k_einsum<<<dim3(1024), dim3(256), 0, stream>>>(S3, wr, wi, S4);
  k_inv_t <<<dim3(1024), dim3(256), 0, stream>>>(S4, S5, twIT);
  k_inv_xy<<<dim3(4096), dim3(256), 0, stream>>>(S5, out, twIX, twIYr, twIYi);
}